// Round 9
// baseline (384.365 us; speedup 1.0000x reference)
//
#include <hip/hip_runtime.h>
#include <hip/hip_bf16.h>

typedef __attribute__((ext_vector_type(8))) short short8;   // 8 bf16 (4 VGPRs)
typedef __attribute__((ext_vector_type(4))) float f32x4;    // MFMA acc

#define NH   4
#define NB   1024
#define NL   200
#define NDQ  512
#define NDF  128
#define ND1  128
#define ND2  64
#define KP   128            // k-stride (bf16 elems); conflicts handled by rotation swizzle
#define NW   13             // active warps = M-tiles (13*16 = 208 >= 200 rows)
#define NT   (NW*64)        // 832 threads
#define HIMG (3*ND2*KP*2)   // bytes per head weight image (49152)
#define SGRAN (3*ND2*16)    // 3072 float4 granules per head image

// workspace layout (bytes)
#define OFF_WQC   0                                    // fp32 [H][512][64]   524288
#define OFF_BQC   (NH*NDQ*ND2*4)                       // fp32 [H][64]
#define OFF_FQ    (OFF_BQC + NH*ND2*4)                 // fp32 [H][B][64]
#define OFF_WIMG  (OFF_FQ + NH*NB*ND2*4)               // bf16 [H][3][64][KP] (slots: Wf_hi, Wf_lo, Wv_hi)
#define OFF_BFC   (OFF_WIMG + NH*HIMG)                 // fp32 [H][64]
#define OFF_BVC   (OFF_BFC + NH*ND2*4)                 // fp32 [H][64]

// global->LDS DMA: per-lane GLOBAL address, wave-uniform LDS base + lane*16
#define GLOAD_LDS16(gp, lp) __builtin_amdgcn_global_load_lds(                 \
    (const __attribute__((address_space(1))) void*)(gp),                      \
    (__attribute__((address_space(3))) void*)(lp), 16, 0, 0)

__device__ inline short f2bf(float f) {                // RN-even fp32 -> bf16 bits
    union { float f; unsigned u; } v; v.f = f;
    unsigned r = (v.u + 0x7FFFu + ((v.u >> 16) & 1u)) >> 16;
    return (short)r;
}
__device__ inline float bf2f(short s) {
    union { unsigned u; float f; } v; v.u = ((unsigned)(unsigned short)s) << 16;
    return v.f;
}
__device__ inline float fsilu(float z) {               // fast silu
    return z * __fdividef(1.f, 1.f + __expf(-z));
}

// ---- cross-lane reductions on the VALU (no DS pipe) ----
template<int CTRL>
__device__ inline float dppf(float x) {                // DPP-moved copy of x
    return __int_as_float(__builtin_amdgcn_update_dpp(0, __float_as_int(x), CTRL, 0xF, 0xF, true));
}
__device__ inline float red16_add(float s) {
    s += dppf<0xB1>(s);      // quad_perm [1,0,3,2]  (xor1)
    s += dppf<0x4E>(s);      // quad_perm [2,3,0,1]  (xor2)
    s += dppf<0x141>(s);     // row_half_mirror
    s += dppf<0x140>(s);     // row_mirror
    return s;
}
__device__ inline float swap16_add(float x) {
    auto p = __builtin_amdgcn_permlane16_swap(__float_as_uint(x), __float_as_uint(x), false, false);
    return __uint_as_float(p[0]) + __uint_as_float(p[1]);
}
__device__ inline float swap32_add(float x) {
    auto p = __builtin_amdgcn_permlane32_swap(__float_as_uint(x), __float_as_uint(x), false, false);
    return __uint_as_float(p[0]) + __uint_as_float(p[1]);
}
__device__ inline float swap16_max(float x) {
    auto p = __builtin_amdgcn_permlane16_swap(__float_as_uint(x), __float_as_uint(x), false, false);
    return fmaxf(__uint_as_float(p[0]), __uint_as_float(p[1]));
}
__device__ inline float swap32_max(float x) {
    auto p = __builtin_amdgcn_permlane32_swap(__float_as_uint(x), __float_as_uint(x), false, false);
    return fmaxf(__uint_as_float(p[0]), __uint_as_float(p[1]));
}

// ---------------- K1: fuse weights (identity between FC layers) ----------------
__global__ __launch_bounds__(256) void k_combine(
    const float* __restrict__ Wq1, const float* __restrict__ bq1,
    const float* __restrict__ Wq2, const float* __restrict__ bq2,
    const float* __restrict__ Wf1, const float* __restrict__ bf1,
    const float* __restrict__ Wf2, const float* __restrict__ bf2,
    const float* __restrict__ Wv1, const float* __restrict__ bv1,
    const float* __restrict__ Wv2, const float* __restrict__ bv2,
    float* __restrict__ WQC, float* __restrict__ BQC,
    __hip_bfloat16* __restrict__ WIMG, float* __restrict__ BFC, float* __restrict__ BVC)
{
    int g = blockIdx.x * 256 + threadIdx.x;
    if (g < NH*NDQ*ND2) {                       // Wqc = Wq1@Wq2 (fp32 exact)
        int h = g >> 15, r = g & 32767, i = r >> 6, j = r & 63;
        const float* a  = Wq1 + (h*NDQ + i)*ND1;
        const float* bb = Wq2 + h*ND1*ND2 + j;
        float s = 0.f;
        for (int k = 0; k < ND1; ++k) s += a[k] * bb[k*ND2];
        WQC[(h*NDQ + i)*ND2 + j] = s;
        return;
    }
    g -= NH*NDQ*ND2;
    if (g < 2*NH*NDF*ND2) {                     // Wfc (hi+lo) / Wvc (hi), transposed image
        int which = (g >= NH*NDF*ND2);
        int r0 = g & (NH*NDF*ND2 - 1);
        int h = r0 >> 13, r = r0 & 8191, i = r >> 6, j = r & 63;
        const float* W1 = (which ? Wv1 : Wf1) + (h*NDF + i)*ND1;
        const float* W2 = (which ? Wv2 : Wf2) + h*ND1*ND2 + j;
        float s = 0.f;
        for (int k = 0; k < ND1; ++k) s += W1[k] * W2[k*ND2];
        short hi = f2bf(s);
        short lo = f2bf(s - bf2f(hi));
        __hip_bfloat16* img = WIMG + (size_t)((h*3 + (which ? 2 : 0))*ND2 + j)*KP + i; // [col=j][k=i]
        ((short*)img)[0] = hi;
        if (!which) ((short*)img)[ND2*KP] = lo;  // Wf lo slot
        return;
    }
    g -= 2*NH*NDF*ND2;
    if (g < NH*ND2) {                           // bqc = bq1@Wq2 + bq2
        int h = g >> 6, j = g & 63;
        float s = bq2[h*ND2 + j];
        for (int k = 0; k < ND1; ++k) s += bq1[h*ND1 + k] * Wq2[(h*ND1 + k)*ND2 + j];
        BQC[g] = s; return;
    }
    g -= NH*ND2;
    if (g < NH*ND2) {
        int h = g >> 6, j = g & 63;
        float s = bf2[h*ND2 + j];
        for (int k = 0; k < ND1; ++k) s += bf1[h*ND1 + k] * Wf2[(h*ND1 + k)*ND2 + j];
        BFC[g] = s; return;
    }
    g -= NH*ND2;
    if (g < NH*ND2) {
        int h = g >> 6, j = g & 63;
        float s = bv2[h*ND2 + j];
        for (int k = 0; k < ND1; ++k) s += bv1[h*ND1 + k] * Wv2[(h*ND1 + k)*ND2 + j];
        BVC[g] = s; return;
    }
}

// ---------------- K2: fq = silu(q @ Wqc + bqc) ----------------
__global__ __launch_bounds__(256) void k_fq(
    const float* __restrict__ query, const float* __restrict__ WQC,
    const float* __restrict__ BQC, float* __restrict__ FQ)
{
    __shared__ __align__(16) float qS[2*NDQ];
    const int t = threadIdx.x;
    const int b0 = blockIdx.x * 2;
    {
        const float4* src = (const float4*)(query + (size_t)b0 * NDQ);
        ((float4*)qS)[t] = src[t];              // 256 float4 = 2 x 512 floats
    }
    __syncthreads();
    const int h = t >> 6, d = t & 63;
    float s0, s1;
    s0 = s1 = BQC[h*ND2 + d];
    const float* wp = WQC + (size_t)h*NDQ*ND2 + d;
    #pragma unroll 16
    for (int i = 0; i < NDQ; ++i) {
        float wv = wp[i*ND2];
        s0 += qS[i]       * wv;
        s1 += qS[NDQ + i] * wv;
    }
    float* o = FQ + ((size_t)h*NB + b0)*ND2 + d;
    o[0]   = fsilu(s0);
    o[ND2] = fsilu(s1);
}

// ---------------- K3: main fused attention, 2-head software pipeline ----------------
// 832 threads (13 warps), one M-tile/warp, one b per block.
// T15 pipeline: each phase runs {GEMMs of head h+1 (MFMA + ds_read)} in
// parallel with {finish of head h (epilogue/softmax/AV — pure VALU on
// registers)}. Breaks the DS-burst -> MFMA-burst -> VALU-burst lockstep
// that left every pipe <50% busy (R6/R7: phase 28.5k cy vs 13.7k VALU work).
// Costs a second (accF,accV) set (32 VGPR); waves_per_eu(4,4) caps 128.
// No setprio (it would fence the scheduler between the two streams).
// Weight staging: global_load_lds DMA, inverse-rotation-swizzled source,
// conflict-free reads, double-buffered wS. Math is bit-identical to R7.
__global__ __launch_bounds__(NT) __attribute__((amdgpu_waves_per_eu(4, 4))) void k_main(
    const float* __restrict__ fact,
    const int* __restrict__ mask,
    const float* __restrict__ mmc,
    const float* __restrict__ tau1,
    const float* __restrict__ tau2,
    const float* __restrict__ FQ,
    const float* __restrict__ BFC,
    const float* __restrict__ BVC,
    const __hip_bfloat16* __restrict__ WIMG,
    float* __restrict__ out)
{
    __shared__ __align__(16) __hip_bfloat16 wS[2][3*ND2*KP];  // 2 x 49152 B
    __shared__ __align__(16) float pS[2][NW][132];            // ping-pong: m, s, oE[64], oS[64]
    __shared__ __align__(16) float fqS[NH][ND2];              // 1 KB
    __shared__ __align__(16) float bfcS[NH][ND2];             // 1 KB
    __shared__ __align__(16) float bvcS[NH][ND2];             // 1 KB

    const int t    = threadIdx.x;
    const int b    = blockIdx.x;
    const int w    = t >> 6;                    // 0..12 = M-tile index
    const int lane = t & 63;
    const int a15  = lane & 15;
    const int quad = lane >> 4;
    const int qrot = quad + 2*(a15 & 7);        // read-side swizzle base

    const int bL = b * NL;

    // ---- DMA: wave w owns float4-chunks w*4..w*4+3 (<48); LDS slot i=c*64+lane
    //      takes global granule (row*16 + g), g = ((i&15)-2*(row&7))&15 (inverse swizzle).
    auto DMA = [&](int hh) {
        const char* hb = (const char*)WIMG + (size_t)hh*HIMG;
        char* lb = (char*)&wS[hh & 1][0];
        #pragma unroll
        for (int j = 0; j < 4; ++j) {
            int c = w*4 + j;
            if (c < SGRAN/64) {
                int i = c*64 + lane;
                int row = i >> 4;
                int g = ((i & 15) - 2*(row & 7)) & 15;
                GLOAD_LDS16(hb + (row*16 + g)*16, lb + c*1024);
            }
        }
    };

    DMA(0);                                     // head-0 staging in flight

    // ---- per-head constant loads (FQ/BFC/BVC -> LDS) ----
    float cval = 0.f;
    if (t < 256)       cval = FQ[(((size_t)(t >> 6))*NB + b)*ND2 + (t & 63)];
    else if (t < 512)  cval = BFC[t - 256];
    else if (t < 768)  cval = BVC[t - 512];
    // ---- head-invariant per-row data (mask penalty + cosine terms) ----
    float mkv[4], c0v[4], c1v[4];
    {
        int rbase = w*16 + quad*4;
        for (int rg = 0; rg < 4; ++rg) {
            int r = rbase + rg;
            if (r < NL) {
                mkv[rg] = 1e9f * (1.0f - (float)mask[bL + r]);
                c0v[rg] = mmc[bL + r];
                c1v[rg] = mmc[NB*NL + bL + r];
            } else { mkv[rg] = 0.f; c0v[rg] = 0.f; c1v[rg] = 0.f; }
        }
    }

    // ---- A fragments: this warp's 16 fact rows, hi/lo bf16 ----
    short8 afh[4], afl[4];
    const short8 zero8 = {0,0,0,0,0,0,0,0};
    {
        int row = w*16 + a15;
        for (int kk = 0; kk < 4; ++kk) {
            short8 vh = zero8, vl = zero8;
            if (row < NL) {
                const float* p = fact + ((size_t)(bL + row))*NDF + kk*32 + quad*8;
                float4 x0 = *(const float4*)p;
                float4 x1 = *(const float4*)(p + 4);
                float v[8] = {x0.x, x0.y, x0.z, x0.w, x1.x, x1.y, x1.z, x1.w};
                for (int j = 0; j < 8; ++j) {
                    short hs = f2bf(v[j]);
                    vh[j] = hs;
                    vl[j] = f2bf(v[j] - bf2f(hs));
                }
            }
            afh[kk] = vh;
            afl[kk] = vl;
        }
    }

    if (t < 256)       ((float*)fqS)[t]        = cval;
    else if (t < 512)  ((float*)bfcS)[t - 256] = cval;
    else if (t < 768)  ((float*)bvcS)[t - 512] = cval;
    __syncthreads();                            // wS[0] + consts ready

    const f32x4 zf = {0.f, 0.f, 0.f, 0.f};

    // ---- GEMMs of one head: ff 3-pass (hi*hi + hi*lo + lo*hi) + fv hi*hi ----
    auto GEMMS = [&](f32x4 (&aF)[4], f32x4 (&aV)[4], const __hip_bfloat16* wb) {
        #pragma unroll
        for (int nt = 0; nt < 4; ++nt) { aF[nt] = zf; aV[nt] = zf; }
        #pragma unroll
        for (int kk = 0; kk < 4; ++kk) {
            const int gk = ((kk*4 + qrot) & 15) << 3;
            short8 bh[4], bl[4];
            #pragma unroll
            for (int nt = 0; nt < 4; ++nt) {
                const __hip_bfloat16* p = wb + (nt*16 + a15)*KP + gk;
                bh[nt] = *(const short8*)p;
                bl[nt] = *(const short8*)(p + ND2*KP);
            }
            #pragma unroll
            for (int nt = 0; nt < 4; ++nt) {
                aF[nt] = __builtin_amdgcn_mfma_f32_16x16x32_bf16(afh[kk], bh[nt], aF[nt], 0, 0, 0);
                aF[nt] = __builtin_amdgcn_mfma_f32_16x16x32_bf16(afh[kk], bl[nt], aF[nt], 0, 0, 0);
                aF[nt] = __builtin_amdgcn_mfma_f32_16x16x32_bf16(afl[kk], bh[nt], aF[nt], 0, 0, 0);
            }
        }
        #pragma unroll
        for (int kk = 0; kk < 4; ++kk) {
            const int gk = ((kk*4 + qrot) & 15) << 3;
            short8 bv[4];
            #pragma unroll
            for (int nt = 0; nt < 4; ++nt)
                bv[nt] = *(const short8*)(wb + (2*ND2 + nt*16 + a15)*KP + gk);
            #pragma unroll
            for (int nt = 0; nt < 4; ++nt)
                aV[nt] = __builtin_amdgcn_mfma_f32_16x16x32_bf16(afh[kk], bv[nt], aV[nt], 0, 0, 0);
        }
    };

    // ---- finish one head: epilogue, softmax, AV, pS write (pure VALU) ----
    auto FINISH = [&](f32x4 (&aF)[4], f32x4 (&aV)[4], int h) {
        const float rt1a = __fdividef(1.f, tau1[h]);
        const float rt1b = __fdividef(1.f, tau1[NH + h]);
        const float t20 = tau2[h];
        const float t21 = tau2[NH + h];
        const float t22 = tau2[2*NH + h];
        float fqv[4], bfcv[4], bvcv[4];
        #pragma unroll
        for (int nt = 0; nt < 4; ++nt) {
            fqv[nt]  = fqS[h][nt*16 + a15];
            bfcv[nt] = bfcS[h][nt*16 + a15];
            bvcv[nt] = bvcS[h][nt*16 + a15];
        }
        float lg[4];
        #pragma unroll
        for (int rg = 0; rg < 4; ++rg) {
            float l = -3.0e38f;
            float s = 0.f;
            #pragma unroll
            for (int nt = 0; nt < 4; ++nt)
                s += fsilu(aF[nt][rg] + bfcv[nt]) * fqv[nt];
            s = red16_add(s);
            int r = w*16 + quad*4 + rg;
            if (r < NL) {
                float dv = s - mkv[rg];
                float bias = c0v[rg]*rt1a + c1v[rg]*rt1b;
                l = t20*dv + t21*bias + t22*dv*bias;
            }
            lg[rg] = l;
        }
        float m = fmaxf(fmaxf(lg[0], lg[1]), fmaxf(lg[2], lg[3]));
        m = swap32_max(swap16_max(m));
        float sw = 0.f;
        #pragma unroll
        for (int rg = 0; rg < 4; ++rg) {
            float p = __expf(lg[rg] - m);       // invalid rows underflow to 0
            lg[rg] = p;
            sw += p;
        }
        sw = swap32_add(swap16_add(sw));
        float oE[4] = {0.f,0.f,0.f,0.f}, oS[4] = {0.f,0.f,0.f,0.f};
        #pragma unroll
        for (int rg = 0; rg < 4; ++rg) {
            float p = lg[rg];
            int r = w*16 + quad*4 + rg;
            float vm = (r < NL) ? 1.f : 0.f;
            #pragma unroll
            for (int nt = 0; nt < 4; ++nt) {
                float sv = fsilu(aV[nt][rg] + bvcv[nt]);
                oE[nt] += p * sv;
                oS[nt] += vm * sv;
            }
        }
        #pragma unroll
        for (int nt = 0; nt < 4; ++nt) {
            oE[nt] = swap32_add(swap16_add(oE[nt]));
            oS[nt] = swap32_add(swap16_add(oS[nt]));
        }
        if (lane == 0) { pS[h & 1][w][0] = m; pS[h & 1][w][1] = sw; }
        if (quad == 0)
            #pragma unroll
            for (int nt = 0; nt < 4; ++nt) {
                pS[h & 1][w][2  + nt*16 + a15] = oE[nt];
                pS[h & 1][w][66 + nt*16 + a15] = oS[nt];
            }
    };

    // ---- LSE-merge of 13 warps for head hm (one warp calls this) ----
    auto MERGE = [&](int hm) {
        const int ps = hm & 1;
        float M = pS[ps][0][0];
        for (int ww = 1; ww < NW; ++ww) M = fmaxf(M, pS[ps][ww][0]);
        float den = 0.f, num = 0.f, s1 = 0.f;
        for (int ww = 0; ww < NW; ++ww) {
            float e = __expf(pS[ps][ww][0] - M);
            den += e * pS[ps][ww][1];
            num += e * pS[ps][ww][2 + lane];
            s1  += pS[ps][ww][66 + lane];
        }
        out[(size_t)b*(NH*ND2) + hm*ND2 + lane] = num * __fdividef(1.f, den) + 1e-7f * s1;
    };

    f32x4 aFA[4], aVA[4], aFB[4], aVB[4];

    // phase -1: head 0 GEMMs (no finish to overlap yet)
    DMA(1);
    GEMMS(aFA, aVA, &wS[0][0]);
    __syncthreads();                            // wS[0] reads done; wS[1] ready

    // phase 0: GEMMs head1 || finish head0
    DMA(2);                                     // -> wS[0]
    GEMMS(aFB, aVB, &wS[1][0]);
    FINISH(aFA, aVA, 0);
    __syncthreads();                            // pS[0] ready; wS[1] reads done; wS[0] ready

    // phase 1: GEMMs head2 || finish head1 || merge head0
    DMA(3);                                     // -> wS[1]
    if (w == 9) MERGE(0);
    GEMMS(aFA, aVA, &wS[0][0]);
    FINISH(aFB, aVB, 1);
    __syncthreads();

    // phase 2: GEMMs head3 || finish head2 || merge head1
    if (w == 10) MERGE(1);
    GEMMS(aFB, aVB, &wS[1][0]);
    FINISH(aFA, aVA, 2);
    __syncthreads();

    // phase 3: finish head3 || merge head2
    if (w == 11) MERGE(2);
    FINISH(aFB, aVB, 3);
    __syncthreads();

    if (w == 12) MERGE(3);
}

extern "C" void kernel_launch(void* const* d_in, const int* in_sizes, int n_in,
                              void* d_out, int out_size, void* d_ws, size_t ws_size,
                              hipStream_t stream) {
    const float* query = (const float*)d_in[0];
    const float* fact  = (const float*)d_in[1];
    const int*   maskp = (const int*)d_in[2];
    const float* mmc   = (const float*)d_in[3];
    const float* Wq1 = (const float*)d_in[4];
    const float* bq1 = (const float*)d_in[5];
    const float* Wq2 = (const float*)d_in[6];
    const float* bq2 = (const float*)d_in[7];
    const float* Wf1 = (const float*)d_in[8];
    const float* bf1 = (const float*)d_in[9];
    const float* Wf2 = (const float*)d_in[10];
    const float* bf2 = (const float*)d_in[11];
    const float* Wv1 = (const float*)d_in[12];
    const float* bv1 = (const float*)d_in[13];
    const float* Wv2 = (const float*)d_in[14];
    const float* bv2 = (const float*)d_in[15];
    const float* tau1 = (const float*)d_in[16];
    const float* tau2 = (const float*)d_in[17];

    char* ws = (char*)d_ws;
    float*          WQC  = (float*)(ws + OFF_WQC);
    float*          BQC  = (float*)(ws + OFF_BQC);
    float*          FQ   = (float*)(ws + OFF_FQ);
    __hip_bfloat16* WIMG = (__hip_bfloat16*)(ws + OFF_WIMG);
    float*          BFC  = (float*)(ws + OFF_BFC);
    float*          BVC  = (float*)(ws + OFF_BVC);

    k_combine<<<771, 256, 0, stream>>>(Wq1, bq1, Wq2, bq2, Wf1, bf1, Wf2, bf2,
                                       Wv1, bv1, Wv2, bv2, WQC, BQC, WIMG, BFC, BVC);
    k_fq<<<NB/2, 256, 0, stream>>>(query, WQC, BQC, FQ);
    k_main<<<NB, NT, 0, stream>>>(fact, maskp, mmc, tau1, tau2, FQ, BFC, BVC, WIMG,
                                  (float*)d_out);
}

// Round 10
// 383.077 us; speedup vs baseline: 1.0034x; 1.0034x over previous
//
#include <hip/hip_runtime.h>
#include <hip/hip_bf16.h>

typedef __attribute__((ext_vector_type(8))) short short8;   // 8 bf16 (4 VGPRs)
typedef __attribute__((ext_vector_type(4))) float f32x4;    // MFMA acc

#define NH   4
#define NB   1024
#define NL   200
#define NDQ  512
#define NDF  128
#define ND1  128
#define ND2  64
#define KP   128            // k-stride (bf16 elems); conflicts handled by rotation swizzle
#define NWB  8              // warps per block (512 threads -> co-schedulable, R1 evidence)
#define NTB  (NWB*64)       // 512 threads
#define HIMG (3*ND2*KP*2)   // bytes per head weight image (49152)
#define SGRAN (3*ND2*16)    // 3072 float4 granules per head image

// workspace layout (bytes)
#define OFF_WQC   0                                    // fp32 [H][512][64]   524288
#define OFF_BQC   (NH*NDQ*ND2*4)                       // fp32 [H][64]
#define OFF_FQ    (OFF_BQC + NH*ND2*4)                 // fp32 [H][B][64]
#define OFF_WIMG  (OFF_FQ + NH*NB*ND2*4)               // bf16 [H][3][64][KP] (slots: Wf_hi, Wf_lo, Wv_hi)
#define OFF_BFC   (OFF_WIMG + NH*HIMG)                 // fp32 [H][64]
#define OFF_BVC   (OFF_BFC + NH*ND2*4)                 // fp32 [H][64]
#define OFF_PART  (OFF_BVC + NH*ND2*4)                 // fp32 [B][2][H][132] LSE partials (4.3 MB)

// global->LDS DMA: per-lane GLOBAL address, wave-uniform LDS base + lane*16
#define GLOAD_LDS16(gp, lp) __builtin_amdgcn_global_load_lds(                 \
    (const __attribute__((address_space(1))) void*)(gp),                      \
    (__attribute__((address_space(3))) void*)(lp), 16, 0, 0)

__device__ inline short f2bf(float f) {                // RN-even fp32 -> bf16 bits
    union { float f; unsigned u; } v; v.f = f;
    unsigned r = (v.u + 0x7FFFu + ((v.u >> 16) & 1u)) >> 16;
    return (short)r;
}
__device__ inline float bf2f(short s) {
    union { unsigned u; float f; } v; v.u = ((unsigned)(unsigned short)s) << 16;
    return v.f;
}
__device__ inline float fsilu(float z) {               // fast silu
    return z * __fdividef(1.f, 1.f + __expf(-z));
}

// ---- cross-lane reductions on the VALU (no DS pipe) ----
template<int CTRL>
__device__ inline float dppf(float x) {                // DPP-moved copy of x
    return __int_as_float(__builtin_amdgcn_update_dpp(0, __float_as_int(x), CTRL, 0xF, 0xF, true));
}
__device__ inline float red16_add(float s) {
    s += dppf<0xB1>(s);      // quad_perm [1,0,3,2]  (xor1)
    s += dppf<0x4E>(s);      // quad_perm [2,3,0,1]  (xor2)
    s += dppf<0x141>(s);     // row_half_mirror
    s += dppf<0x140>(s);     // row_mirror
    return s;
}
__device__ inline float swap16_add(float x) {
    auto p = __builtin_amdgcn_permlane16_swap(__float_as_uint(x), __float_as_uint(x), false, false);
    return __uint_as_float(p[0]) + __uint_as_float(p[1]);
}
__device__ inline float swap32_add(float x) {
    auto p = __builtin_amdgcn_permlane32_swap(__float_as_uint(x), __float_as_uint(x), false, false);
    return __uint_as_float(p[0]) + __uint_as_float(p[1]);
}
__device__ inline float swap16_max(float x) {
    auto p = __builtin_amdgcn_permlane16_swap(__float_as_uint(x), __float_as_uint(x), false, false);
    return fmaxf(__uint_as_float(p[0]), __uint_as_float(p[1]));
}
__device__ inline float swap32_max(float x) {
    auto p = __builtin_amdgcn_permlane32_swap(__float_as_uint(x), __float_as_uint(x), false, false);
    return fmaxf(__uint_as_float(p[0]), __uint_as_float(p[1]));
}

// ---------------- K1: fuse weights (identity between FC layers) ----------------
__global__ __launch_bounds__(256) void k_combine(
    const float* __restrict__ Wq1, const float* __restrict__ bq1,
    const float* __restrict__ Wq2, const float* __restrict__ bq2,
    const float* __restrict__ Wf1, const float* __restrict__ bf1,
    const float* __restrict__ Wf2, const float* __restrict__ bf2,
    const float* __restrict__ Wv1, const float* __restrict__ bv1,
    const float* __restrict__ Wv2, const float* __restrict__ bv2,
    float* __restrict__ WQC, float* __restrict__ BQC,
    __hip_bfloat16* __restrict__ WIMG, float* __restrict__ BFC, float* __restrict__ BVC)
{
    int g = blockIdx.x * 256 + threadIdx.x;
    if (g < NH*NDQ*ND2) {                       // Wqc = Wq1@Wq2 (fp32 exact)
        int h = g >> 15, r = g & 32767, i = r >> 6, j = r & 63;
        const float* a  = Wq1 + (h*NDQ + i)*ND1;
        const float* bb = Wq2 + h*ND1*ND2 + j;
        float s = 0.f;
        for (int k = 0; k < ND1; ++k) s += a[k] * bb[k*ND2];
        WQC[(h*NDQ + i)*ND2 + j] = s;
        return;
    }
    g -= NH*NDQ*ND2;
    if (g < 2*NH*NDF*ND2) {                     // Wfc (hi+lo) / Wvc (hi), transposed image
        int which = (g >= NH*NDF*ND2);
        int r0 = g & (NH*NDF*ND2 - 1);
        int h = r0 >> 13, r = r0 & 8191, i = r >> 6, j = r & 63;
        const float* W1 = (which ? Wv1 : Wf1) + (h*NDF + i)*ND1;
        const float* W2 = (which ? Wv2 : Wf2) + h*ND1*ND2 + j;
        float s = 0.f;
        for (int k = 0; k < ND1; ++k) s += W1[k] * W2[k*ND2];
        short hi = f2bf(s);
        short lo = f2bf(s - bf2f(hi));
        __hip_bfloat16* img = WIMG + (size_t)((h*3 + (which ? 2 : 0))*ND2 + j)*KP + i; // [col=j][k=i]
        ((short*)img)[0] = hi;
        if (!which) ((short*)img)[ND2*KP] = lo;  // Wf lo slot
        return;
    }
    g -= 2*NH*NDF*ND2;
    if (g < NH*ND2) {                           // bqc = bq1@Wq2 + bq2
        int h = g >> 6, j = g & 63;
        float s = bq2[h*ND2 + j];
        for (int k = 0; k < ND1; ++k) s += bq1[h*ND1 + k] * Wq2[(h*ND1 + k)*ND2 + j];
        BQC[g] = s; return;
    }
    g -= NH*ND2;
    if (g < NH*ND2) {
        int h = g >> 6, j = g & 63;
        float s = bf2[h*ND2 + j];
        for (int k = 0; k < ND1; ++k) s += bf1[h*ND1 + k] * Wf2[(h*ND1 + k)*ND2 + j];
        BFC[g] = s; return;
    }
    g -= NH*ND2;
    if (g < NH*ND2) {
        int h = g >> 6, j = g & 63;
        float s = bv2[h*ND2 + j];
        for (int k = 0; k < ND1; ++k) s += bv1[h*ND1 + k] * Wv2[(h*ND1 + k)*ND2 + j];
        BVC[g] = s; return;
    }
}

// ---------------- K2: fq = silu(q @ Wqc + bqc) ----------------
__global__ __launch_bounds__(256) void k_fq(
    const float* __restrict__ query, const float* __restrict__ WQC,
    const float* __restrict__ BQC, float* __restrict__ FQ)
{
    __shared__ __align__(16) float qS[2*NDQ];
    const int t = threadIdx.x;
    const int b0 = blockIdx.x * 2;
    {
        const float4* src = (const float4*)(query + (size_t)b0 * NDQ);
        ((float4*)qS)[t] = src[t];              // 256 float4 = 2 x 512 floats
    }
    __syncthreads();
    const int h = t >> 6, d = t & 63;
    float s0, s1;
    s0 = s1 = BQC[h*ND2 + d];
    const float* wp = WQC + (size_t)h*NDQ*ND2 + d;
    #pragma unroll 16
    for (int i = 0; i < NDQ; ++i) {
        float wv = wp[i*ND2];
        s0 += qS[i]       * wv;
        s1 += qS[NDQ + i] * wv;
    }
    float* o = FQ + ((size_t)h*NB + b0)*ND2 + d;
    o[0]   = fsilu(s0);
    o[ND2] = fsilu(s1);
}

// ---------------- K3: main fused attention, split-L for co-residency ----------------
// Grid 2048: block = (b, half). half0 = M-tiles 0..6, half1 = tiles 7..12.
// 512 threads (8 warps), one tile/warp — R1 proved 512-thr blocks at VGPR=64
// DO co-schedule 2/CU (43.7% occ), unlike 832-thr blocks (never >38%). LDS
// ~61 KB -> two blocks fit. Co-resident block fills the pipe bubbles that
// R6/R7 showed (all pipes <50%, phase 2x its committed work).
// Per-warp compute identical to R7 (no-spill at 64 VGPR): DPP/permlane
// reductions, inverse-swizzled global_load_lds, single-buffer wS with
// 2 barriers/head. Block writes LSE partials (M, den, num[64], s1[64]) per
// head; k_merge combines the two halves (associatively regrouped R7 merge).
__global__ __launch_bounds__(NTB) void k_main(
    const float* __restrict__ fact,
    const int* __restrict__ mask,
    const float* __restrict__ mmc,
    const float* __restrict__ tau1,
    const float* __restrict__ tau2,
    const float* __restrict__ FQ,
    const float* __restrict__ BFC,
    const float* __restrict__ BVC,
    const __hip_bfloat16* __restrict__ WIMG,
    float* __restrict__ gws)
{
    __shared__ __align__(16) __hip_bfloat16 wS[3*ND2*KP];     // 49152 B (single buffer)
    __shared__ __align__(16) float pS[2][NWB][132];           // ping-pong: m, s, oE[64], oS[64]
    __shared__ __align__(16) float fqS[NH][ND2];              // 1 KB
    __shared__ __align__(16) float bfcS[NH][ND2];             // 1 KB
    __shared__ __align__(16) float bvcS[NH][ND2];             // 1 KB

    const int t    = threadIdx.x;
    const int blk  = blockIdx.x;
    const int b    = blk >> 1;
    const int half = blk & 1;
    const int w    = t >> 6;
    const int lane = t & 63;
    const int a15  = lane & 15;
    const int quad = lane >> 4;
    const int qrot = quad + 2*(a15 & 7);        // read-side swizzle base

    const int tile = half ? (7 + w) : w;        // this warp's M-tile
    const bool act = half ? (w < 6) : (w < 7);  // 7 + 6 = 13 tiles
    const int bL = b * NL;

    // ---- DMA: wave w owns float4-chunks w*6..w*6+5 (8x6 = 48 exactly).
    //      LDS slot i = c*64+lane takes granule (row*16+g), g = ((i&15)-2*(row&7))&15.
    auto DMA = [&](int hh) {
        const char* hb = (const char*)WIMG + (size_t)hh*HIMG;
        #pragma unroll
        for (int j = 0; j < 6; ++j) {
            int c = w*6 + j;
            int i = c*64 + lane;
            int row = i >> 4;
            int g = ((i & 15) - 2*(row & 7)) & 15;
            GLOAD_LDS16(hb + (row*16 + g)*16, (char*)wS + c*1024);
        }
    };

    DMA(0);                                     // head-0 staging in flight

    // ---- per-head constant loads (FQ/BFC/BVC -> LDS) ----
    float cval = 0.f, cval2 = 0.f;
    if (t < 256) { cval = FQ[(((size_t)(t >> 6))*NB + b)*ND2 + (t & 63)]; cval2 = BVC[t]; }
    else         { cval = BFC[t - 256]; }
    // ---- head-invariant per-row data (mask penalty + cosine terms) ----
    float mkv[4], c0v[4], c1v[4];
    {
        int rbase = tile*16 + quad*4;
        for (int rg = 0; rg < 4; ++rg) {
            int r = rbase + rg;
            if (act && r < NL) {
                mkv[rg] = 1e9f * (1.0f - (float)mask[bL + r]);
                c0v[rg] = mmc[bL + r];
                c1v[rg] = mmc[NB*NL + bL + r];
            } else { mkv[rg] = 0.f; c0v[rg] = 0.f; c1v[rg] = 0.f; }
        }
    }

    // ---- A fragments: this warp's 16 fact rows, hi/lo bf16 ----
    short8 afh[4], afl[4];
    const short8 zero8 = {0,0,0,0,0,0,0,0};
    {
        int row = tile*16 + a15;
        for (int kk = 0; kk < 4; ++kk) {
            short8 vh = zero8, vl = zero8;
            if (act && row < NL) {
                const float* p = fact + ((size_t)(bL + row))*NDF + kk*32 + quad*8;
                float4 x0 = *(const float4*)p;
                float4 x1 = *(const float4*)(p + 4);
                float v[8] = {x0.x, x0.y, x0.z, x0.w, x1.x, x1.y, x1.z, x1.w};
                for (int j = 0; j < 8; ++j) {
                    short hs = f2bf(v[j]);
                    vh[j] = hs;
                    vl[j] = f2bf(v[j] - bf2f(hs));
                }
            }
            afh[kk] = vh;
            afl[kk] = vl;
        }
    }

    if (t < 256) { ((float*)fqS)[t] = cval; ((float*)bvcS)[t] = cval2; }
    else         { ((float*)bfcS)[t - 256] = cval; }
    __syncthreads();                            // wS (head 0) + consts ready

    const f32x4 zf = {0.f, 0.f, 0.f, 0.f};

    for (int h = 0; h < NH; ++h) {
        if (act) {
            const float rt1a = __fdividef(1.f, tau1[h]);
            const float rt1b = __fdividef(1.f, tau1[NH + h]);
            const float t20 = tau2[h];
            const float t21 = tau2[NH + h];
            const float t22 = tau2[2*NH + h];
            float fqv[4], bfcv[4], bvcv[4];
            #pragma unroll
            for (int nt = 0; nt < 4; ++nt) {
                fqv[nt]  = fqS[h][nt*16 + a15];
                bfcv[nt] = bfcS[h][nt*16 + a15];
                bvcv[nt] = bvcS[h][nt*16 + a15];
            }

            // ---- ff GEMM, 3 passes: f_hi*w_hi + f_hi*w_lo + f_lo*w_hi ----
            f32x4 acc[4];
            #pragma unroll
            for (int nt = 0; nt < 4; ++nt) acc[nt] = zf;
            #pragma unroll
            for (int kk = 0; kk < 4; ++kk) {
                const int gk = ((kk*4 + qrot) & 15) << 3;
                short8 bh[4], bl[4];
                #pragma unroll
                for (int nt = 0; nt < 4; ++nt) {
                    const __hip_bfloat16* p = wS + (nt*16 + a15)*KP + gk;
                    bh[nt] = *(const short8*)p;
                    bl[nt] = *(const short8*)(p + ND2*KP);
                }
                #pragma unroll
                for (int nt = 0; nt < 4; ++nt) {
                    acc[nt] = __builtin_amdgcn_mfma_f32_16x16x32_bf16(afh[kk], bh[nt], acc[nt], 0, 0, 0);
                    acc[nt] = __builtin_amdgcn_mfma_f32_16x16x32_bf16(afh[kk], bl[nt], acc[nt], 0, 0, 0);
                    acc[nt] = __builtin_amdgcn_mfma_f32_16x16x32_bf16(afl[kk], bh[nt], acc[nt], 0, 0, 0);
                }
            }

            // ---- epilogue: silu, dot with fq, mask + cosine bias -> logits ----
            float lg[4];
            #pragma unroll
            for (int rg = 0; rg < 4; ++rg) {
                float l = -3.0e38f;
                float s = 0.f;
                #pragma unroll
                for (int nt = 0; nt < 4; ++nt)
                    s += fsilu(acc[nt][rg] + bfcv[nt]) * fqv[nt];
                s = red16_add(s);
                int r = tile*16 + quad*4 + rg;
                if (r < NL) {
                    float dv = s - mkv[rg];
                    float bias = c0v[rg]*rt1a + c1v[rg]*rt1b;
                    l = t20*dv + t21*bias + t22*dv*bias;
                }
                lg[rg] = l;
            }

            // ---- warp-local softmax over own 16 rows ----
            float m = fmaxf(fmaxf(lg[0], lg[1]), fmaxf(lg[2], lg[3]));
            m = swap32_max(swap16_max(m));
            float sw = 0.f;
            #pragma unroll
            for (int rg = 0; rg < 4; ++rg) {
                float p = __expf(lg[rg] - m);   // invalid rows underflow to 0
                lg[rg] = p;
                sw += p;
            }
            sw = swap32_add(swap16_add(sw));

            // ---- fv GEMM: single hi*hi pass (slot 2), reuse acc ----
            #pragma unroll
            for (int nt = 0; nt < 4; ++nt) acc[nt] = zf;
            #pragma unroll
            for (int kk = 0; kk < 4; ++kk) {
                const int gk = ((kk*4 + qrot) & 15) << 3;
                short8 bv[4];
                #pragma unroll
                for (int nt = 0; nt < 4; ++nt)
                    bv[nt] = *(const short8*)(wS + (2*ND2 + nt*16 + a15)*KP + gk);
                #pragma unroll
                for (int nt = 0; nt < 4; ++nt)
                    acc[nt] = __builtin_amdgcn_mfma_f32_16x16x32_bf16(afh[kk], bv[nt], acc[nt], 0, 0, 0);
            }

            // ---- AV: oE = sum p*silu(fv), oS = sum silu(fv) ----
            float oE[4] = {0.f,0.f,0.f,0.f}, oS[4] = {0.f,0.f,0.f,0.f};
            #pragma unroll
            for (int rg = 0; rg < 4; ++rg) {
                float p = lg[rg];
                int r = tile*16 + quad*4 + rg;
                float vm = (r < NL) ? 1.f : 0.f;
                #pragma unroll
                for (int nt = 0; nt < 4; ++nt) {
                    float sv = fsilu(acc[nt][rg] + bvcv[nt]);
                    oE[nt] += p * sv;
                    oS[nt] += vm * sv;
                }
            }
            #pragma unroll
            for (int nt = 0; nt < 4; ++nt) {
                oE[nt] = swap32_add(swap16_add(oE[nt]));
                oS[nt] = swap32_add(swap16_add(oS[nt]));
            }
            if (lane == 0) { pS[h & 1][w][0] = m; pS[h & 1][w][1] = sw; }
            if (quad == 0)
                #pragma unroll
                for (int nt = 0; nt < 4; ++nt) {
                    pS[h & 1][w][2  + nt*16 + a15] = oE[nt];
                    pS[h & 1][w][66 + nt*16 + a15] = oS[nt];
                }
        }
        __syncthreads();                        // bar1: pS[h&1] ready; wS reads done

        if (h + 1 < NH) DMA(h + 1);             // restage wS (drained by bar2)

        if (w == 7) {                           // block-local LSE merge (overlaps DMA)
            const int ps = h & 1;
            const int nAct = half ? 6 : 7;
            float M = pS[ps][0][0];
            for (int ww = 1; ww < nAct; ++ww) M = fmaxf(M, pS[ps][ww][0]);
            float den = 0.f, num = 0.f, s1 = 0.f;
            for (int ww = 0; ww < nAct; ++ww) {
                float e = __expf(pS[ps][ww][0] - M);
                den += e * pS[ps][ww][1];
                num += e * pS[ps][ww][2 + lane];
                s1  += pS[ps][ww][66 + lane];
            }
            float* gp = gws + (((size_t)b*2 + half)*NH + h)*132;
            if (lane == 0) { gp[0] = M; gp[1] = den; }
            gp[2 + lane]  = num;
            gp[66 + lane] = s1;
        }
        __syncthreads();                        // bar2: wS(h+1) staged
    }
}

// ---------------- K4: merge the two L-halves per (b,h) ----------------
__global__ __launch_bounds__(256) void k_merge(
    const float* __restrict__ gws, float* __restrict__ out)
{
    const int b = blockIdx.x, t = threadIdx.x;
    const int h = t >> 6, d = t & 63;
    const float* A = gws + (((size_t)b*2 + 0)*NH + h)*132;
    const float* B = gws + (((size_t)b*2 + 1)*NH + h)*132;
    float MA = A[0], MB = B[0];
    float M  = fmaxf(MA, MB);
    float eA = __expf(MA - M), eB = __expf(MB - M);
    float den = eA*A[1] + eB*B[1];
    float num = eA*A[2 + d] + eB*B[2 + d];
    float s1  = A[66 + d] + B[66 + d];
    out[(size_t)b*(NH*ND2) + h*ND2 + d] = num * __fdividef(1.f, den) + 1e-7f * s1;
}

extern "C" void kernel_launch(void* const* d_in, const int* in_sizes, int n_in,
                              void* d_out, int out_size, void* d_ws, size_t ws_size,
                              hipStream_t stream) {
    const float* query = (const float*)d_in[0];
    const float* fact  = (const float*)d_in[1];
    const int*   maskp = (const int*)d_in[2];
    const float* mmc   = (const float*)d_in[3];
    const float* Wq1 = (const float*)d_in[4];
    const float* bq1 = (const float*)d_in[5];
    const float* Wq2 = (const float*)d_in[6];
    const float* bq2 = (const float*)d_in[7];
    const float* Wf1 = (const float*)d_in[8];
    const float* bf1 = (const float*)d_in[9];
    const float* Wf2 = (const float*)d_in[10];
    const float* bf2 = (const float*)d_in[11];
    const float* Wv1 = (const float*)d_in[12];
    const float* bv1 = (const float*)d_in[13];
    const float* Wv2 = (const float*)d_in[14];
    const float* bv2 = (const float*)d_in[15];
    const float* tau1 = (const float*)d_in[16];
    const float* tau2 = (const float*)d_in[17];

    char* ws = (char*)d_ws;
    float*          WQC  = (float*)(ws + OFF_WQC);
    float*          BQC  = (float*)(ws + OFF_BQC);
    float*          FQ   = (float*)(ws + OFF_FQ);
    __hip_bfloat16* WIMG = (__hip_bfloat16*)(ws + OFF_WIMG);
    float*          BFC  = (float*)(ws + OFF_BFC);
    float*          BVC  = (float*)(ws + OFF_BVC);
    float*          PART = (float*)(ws + OFF_PART);

    k_combine<<<771, 256, 0, stream>>>(Wq1, bq1, Wq2, bq2, Wf1, bf1, Wf2, bf2,
                                       Wv1, bv1, Wv2, bv2, WQC, BQC, WIMG, BFC, BVC);
    k_fq<<<NB/2, 256, 0, stream>>>(query, WQC, BQC, FQ);
    k_main<<<NB*2, NTB, 0, stream>>>(fact, maskp, mmc, tau1, tau2, FQ, BFC, BVC, WIMG,
                                     PART);
    k_merge<<<NB, 256, 0, stream>>>(PART, (float*)d_out);
}

// Round 11
// 380.892 us; speedup vs baseline: 1.0091x; 1.0057x over previous
//
#include <hip/hip_runtime.h>
#include <hip/hip_bf16.h>

typedef __attribute__((ext_vector_type(8))) short short8;   // 8 bf16 (4 VGPRs)
typedef __attribute__((ext_vector_type(4))) float f32x4;    // MFMA acc

#define NH   4
#define NB   1024
#define NL   200
#define NDQ  512
#define NDF  128
#define ND1  128
#define ND2  64
#define KP   128            // k-stride (bf16 elems); conflicts handled by rotation swizzle
#define NWB  8              // warps per block (512 threads -> co-schedulable at small LDS)
#define NTB  (NWB*64)       // 512 threads
#define HIMG (3*ND2*KP*2)   // bytes per head weight image (49152)
#define SGRAN (3*ND2*16)    // 3072 float4 granules per head image

// workspace layout (bytes)
#define OFF_WQC   0                                    // fp32 [H][512][64]   524288
#define OFF_BQC   (NH*NDQ*ND2*4)                       // fp32 [H][64]
#define OFF_FQ    (OFF_BQC + NH*ND2*4)                 // fp32 [H][B][64]
#define OFF_WIMG  (OFF_FQ + NH*NB*ND2*4)               // bf16 [H][3][64][KP] (slots: Wf_hi, Wf_lo, Wv_hi)
#define OFF_BFC   (OFF_WIMG + NH*HIMG)                 // fp32 [H][64]
#define OFF_BVC   (OFF_BFC + NH*ND2*4)                 // fp32 [H][64]
#define OFF_PART  (OFF_BVC + NH*ND2*4)                 // fp32 [B][2][H][132] LSE partials (4.3 MB)

// global->LDS DMA: per-lane GLOBAL address, wave-uniform LDS base + lane*16
#define GLOAD_LDS16(gp, lp) __builtin_amdgcn_global_load_lds(                 \
    (const __attribute__((address_space(1))) void*)(gp),                      \
    (__attribute__((address_space(3))) void*)(lp), 16, 0, 0)

__device__ inline short f2bf(float f) {                // RN-even fp32 -> bf16 bits
    union { float f; unsigned u; } v; v.f = f;
    unsigned r = (v.u + 0x7FFFu + ((v.u >> 16) & 1u)) >> 16;
    return (short)r;
}
__device__ inline float bf2f(short s) {
    union { unsigned u; float f; } v; v.u = ((unsigned)(unsigned short)s) << 16;
    return v.f;
}
__device__ inline float fsilu(float z) {               // fast silu
    return z * __fdividef(1.f, 1.f + __expf(-z));
}

// ---- cross-lane reductions on the VALU (no DS pipe) ----
template<int CTRL>
__device__ inline float dppf(float x) {                // DPP-moved copy of x
    return __int_as_float(__builtin_amdgcn_update_dpp(0, __float_as_int(x), CTRL, 0xF, 0xF, true));
}
__device__ inline float red16_add(float s) {
    s += dppf<0xB1>(s);      // quad_perm [1,0,3,2]  (xor1)
    s += dppf<0x4E>(s);      // quad_perm [2,3,0,1]  (xor2)
    s += dppf<0x141>(s);     // row_half_mirror
    s += dppf<0x140>(s);     // row_mirror
    return s;
}
__device__ inline float swap16_add(float x) {
    auto p = __builtin_amdgcn_permlane16_swap(__float_as_uint(x), __float_as_uint(x), false, false);
    return __uint_as_float(p[0]) + __uint_as_float(p[1]);
}
__device__ inline float swap32_add(float x) {
    auto p = __builtin_amdgcn_permlane32_swap(__float_as_uint(x), __float_as_uint(x), false, false);
    return __uint_as_float(p[0]) + __uint_as_float(p[1]);
}
__device__ inline float swap16_max(float x) {
    auto p = __builtin_amdgcn_permlane16_swap(__float_as_uint(x), __float_as_uint(x), false, false);
    return fmaxf(__uint_as_float(p[0]), __uint_as_float(p[1]));
}
__device__ inline float swap32_max(float x) {
    auto p = __builtin_amdgcn_permlane32_swap(__float_as_uint(x), __float_as_uint(x), false, false);
    return fmaxf(__uint_as_float(p[0]), __uint_as_float(p[1]));
}

// ---------------- K1: fuse weights (identity between FC layers) ----------------
__global__ __launch_bounds__(256) void k_combine(
    const float* __restrict__ Wq1, const float* __restrict__ bq1,
    const float* __restrict__ Wq2, const float* __restrict__ bq2,
    const float* __restrict__ Wf1, const float* __restrict__ bf1,
    const float* __restrict__ Wf2, const float* __restrict__ bf2,
    const float* __restrict__ Wv1, const float* __restrict__ bv1,
    const float* __restrict__ Wv2, const float* __restrict__ bv2,
    float* __restrict__ WQC, float* __restrict__ BQC,
    __hip_bfloat16* __restrict__ WIMG, float* __restrict__ BFC, float* __restrict__ BVC)
{
    int g = blockIdx.x * 256 + threadIdx.x;
    if (g < NH*NDQ*ND2) {                       // Wqc = Wq1@Wq2 (fp32 exact)
        int h = g >> 15, r = g & 32767, i = r >> 6, j = r & 63;
        const float* a  = Wq1 + (h*NDQ + i)*ND1;
        const float* bb = Wq2 + h*ND1*ND2 + j;
        float s = 0.f;
        for (int k = 0; k < ND1; ++k) s += a[k] * bb[k*ND2];
        WQC[(h*NDQ + i)*ND2 + j] = s;
        return;
    }
    g -= NH*NDQ*ND2;
    if (g < 2*NH*NDF*ND2) {                     // Wfc (hi+lo) / Wvc (hi), transposed image
        int which = (g >= NH*NDF*ND2);
        int r0 = g & (NH*NDF*ND2 - 1);
        int h = r0 >> 13, r = r0 & 8191, i = r >> 6, j = r & 63;
        const float* W1 = (which ? Wv1 : Wf1) + (h*NDF + i)*ND1;
        const float* W2 = (which ? Wv2 : Wf2) + h*ND1*ND2 + j;
        float s = 0.f;
        for (int k = 0; k < ND1; ++k) s += W1[k] * W2[k*ND2];
        short hi = f2bf(s);
        short lo = f2bf(s - bf2f(hi));
        __hip_bfloat16* img = WIMG + (size_t)((h*3 + (which ? 2 : 0))*ND2 + j)*KP + i; // [col=j][k=i]
        ((short*)img)[0] = hi;
        if (!which) ((short*)img)[ND2*KP] = lo;  // Wf lo slot
        return;
    }
    g -= 2*NH*NDF*ND2;
    if (g < NH*ND2) {                           // bqc = bq1@Wq2 + bq2
        int h = g >> 6, j = g & 63;
        float s = bq2[h*ND2 + j];
        for (int k = 0; k < ND1; ++k) s += bq1[h*ND1 + k] * Wq2[(h*ND1 + k)*ND2 + j];
        BQC[g] = s; return;
    }
    g -= NH*ND2;
    if (g < NH*ND2) {
        int h = g >> 6, j = g & 63;
        float s = bf2[h*ND2 + j];
        for (int k = 0; k < ND1; ++k) s += bf1[h*ND1 + k] * Wf2[(h*ND1 + k)*ND2 + j];
        BFC[g] = s; return;
    }
    g -= NH*ND2;
    if (g < NH*ND2) {
        int h = g >> 6, j = g & 63;
        float s = bv2[h*ND2 + j];
        for (int k = 0; k < ND1; ++k) s += bv1[h*ND1 + k] * Wv2[(h*ND1 + k)*ND2 + j];
        BVC[g] = s; return;
    }
}

// ---------------- K2: fq = silu(q @ Wqc + bqc) ----------------
__global__ __launch_bounds__(256) void k_fq(
    const float* __restrict__ query, const float* __restrict__ WQC,
    const float* __restrict__ BQC, float* __restrict__ FQ)
{
    __shared__ __align__(16) float qS[2*NDQ];
    const int t = threadIdx.x;
    const int b0 = blockIdx.x * 2;
    {
        const float4* src = (const float4*)(query + (size_t)b0 * NDQ);
        ((float4*)qS)[t] = src[t];              // 256 float4 = 2 x 512 floats
    }
    __syncthreads();
    const int h = t >> 6, d = t & 63;
    float s0, s1;
    s0 = s1 = BQC[h*ND2 + d];
    const float* wp = WQC + (size_t)h*NDQ*ND2 + d;
    #pragma unroll 16
    for (int i = 0; i < NDQ; ++i) {
        float wv = wp[i*ND2];
        s0 += qS[i]       * wv;
        s1 += qS[NDQ + i] * wv;
    }
    float* o = FQ + ((size_t)h*NB + b0)*ND2 + d;
    o[0]   = fsilu(s0);
    o[ND2] = fsilu(s1);
}

// ---------------- K3: main fused attention, split-L for co-residency ----------------
// Grid 2048: block = (b, half). half0 = M-tiles 0..6, half1 = tiles 7..12.
// 512 threads (8 warps), one tile/warp. CO-RESIDENCY FIX vs R10: the 2-block/CU
// LDS threshold sits between 113.7 KB (R1: 2x56832, occ 43.7%) and 121.9 KB
// (R10: 2x60928, occ 23%). Single pS[7] instead of ping-pong pS[2][8] (safe:
// head h's merge-read lies between bar1(h) and bar2(h); head h+1's pS writes
// come after bar2(h)) trims LDS to ~55.9 KB -> 2x = 111.8 KB < threshold.
// Two co-resident blocks have INDEPENDENT barriers: one block's DMA drain
// overlaps the other's GEMM/VALU -> fills the bubbles (all pipes <50% busy).
// Per-warp compute identical to R7/R10 (no-spill): DPP/permlane reductions,
// inverse-swizzled global_load_lds, 2 barriers/head. Block writes LSE
// partials; k_merge combines the two halves.
__global__ __launch_bounds__(NTB) void k_main(
    const float* __restrict__ fact,
    const int* __restrict__ mask,
    const float* __restrict__ mmc,
    const float* __restrict__ tau1,
    const float* __restrict__ tau2,
    const float* __restrict__ FQ,
    const float* __restrict__ BFC,
    const float* __restrict__ BVC,
    const __hip_bfloat16* __restrict__ WIMG,
    float* __restrict__ gws)
{
    __shared__ __align__(16) __hip_bfloat16 wS[3*ND2*KP];     // 49152 B (single buffer)
    __shared__ __align__(16) float pS[7][132];                // 3696 B: m, s, oE[64], oS[64]
    __shared__ __align__(16) float fqS[NH][ND2];              // 1 KB
    __shared__ __align__(16) float bfcS[NH][ND2];             // 1 KB
    __shared__ __align__(16) float bvcS[NH][ND2];             // 1 KB

    const int t    = threadIdx.x;
    const int blk  = blockIdx.x;
    const int b    = blk >> 1;
    const int half = blk & 1;
    const int w    = t >> 6;
    const int lane = t & 63;
    const int a15  = lane & 15;
    const int quad = lane >> 4;
    const int qrot = quad + 2*(a15 & 7);        // read-side swizzle base

    const int tile = half ? (7 + w) : w;        // this warp's M-tile
    const bool act = half ? (w < 6) : (w < 7);  // 7 + 6 = 13 tiles
    const int bL = b * NL;

    // ---- DMA: wave w owns float4-chunks w*6..w*6+5 (8x6 = 48 exactly).
    //      LDS slot i = c*64+lane takes granule (row*16+g), g = ((i&15)-2*(row&7))&15.
    auto DMA = [&](int hh) {
        const char* hb = (const char*)WIMG + (size_t)hh*HIMG;
        #pragma unroll
        for (int j = 0; j < 6; ++j) {
            int c = w*6 + j;
            int i = c*64 + lane;
            int row = i >> 4;
            int g = ((i & 15) - 2*(row & 7)) & 15;
            GLOAD_LDS16(hb + (row*16 + g)*16, (char*)wS + c*1024);
        }
    };

    DMA(0);                                     // head-0 staging in flight

    // ---- per-head constant loads (FQ/BFC/BVC -> LDS) ----
    float cval = 0.f, cval2 = 0.f;
    if (t < 256) { cval = FQ[(((size_t)(t >> 6))*NB + b)*ND2 + (t & 63)]; cval2 = BVC[t]; }
    else         { cval = BFC[t - 256]; }
    // ---- head-invariant per-row data (mask penalty + cosine terms) ----
    float mkv[4], c0v[4], c1v[4];
    {
        int rbase = tile*16 + quad*4;
        for (int rg = 0; rg < 4; ++rg) {
            int r = rbase + rg;
            if (act && r < NL) {
                mkv[rg] = 1e9f * (1.0f - (float)mask[bL + r]);
                c0v[rg] = mmc[bL + r];
                c1v[rg] = mmc[NB*NL + bL + r];
            } else { mkv[rg] = 0.f; c0v[rg] = 0.f; c1v[rg] = 0.f; }
        }
    }

    // ---- A fragments: this warp's 16 fact rows, hi/lo bf16 ----
    short8 afh[4], afl[4];
    const short8 zero8 = {0,0,0,0,0,0,0,0};
    {
        int row = tile*16 + a15;
        for (int kk = 0; kk < 4; ++kk) {
            short8 vh = zero8, vl = zero8;
            if (act && row < NL) {
                const float* p = fact + ((size_t)(bL + row))*NDF + kk*32 + quad*8;
                float4 x0 = *(const float4*)p;
                float4 x1 = *(const float4*)(p + 4);
                float v[8] = {x0.x, x0.y, x0.z, x0.w, x1.x, x1.y, x1.z, x1.w};
                for (int j = 0; j < 8; ++j) {
                    short hs = f2bf(v[j]);
                    vh[j] = hs;
                    vl[j] = f2bf(v[j] - bf2f(hs));
                }
            }
            afh[kk] = vh;
            afl[kk] = vl;
        }
    }

    if (t < 256) { ((float*)fqS)[t] = cval; ((float*)bvcS)[t] = cval2; }
    else         { ((float*)bfcS)[t - 256] = cval; }
    __syncthreads();                            // wS (head 0) + consts ready

    const f32x4 zf = {0.f, 0.f, 0.f, 0.f};

    for (int h = 0; h < NH; ++h) {
        if (act) {
            const float rt1a = __fdividef(1.f, tau1[h]);
            const float rt1b = __fdividef(1.f, tau1[NH + h]);
            const float t20 = tau2[h];
            const float t21 = tau2[NH + h];
            const float t22 = tau2[2*NH + h];
            float fqv[4], bfcv[4], bvcv[4];
            #pragma unroll
            for (int nt = 0; nt < 4; ++nt) {
                fqv[nt]  = fqS[h][nt*16 + a15];
                bfcv[nt] = bfcS[h][nt*16 + a15];
                bvcv[nt] = bvcS[h][nt*16 + a15];
            }

            // ---- ff GEMM, 3 passes: f_hi*w_hi + f_hi*w_lo + f_lo*w_hi ----
            f32x4 acc[4];
            #pragma unroll
            for (int nt = 0; nt < 4; ++nt) acc[nt] = zf;
            #pragma unroll
            for (int kk = 0; kk < 4; ++kk) {
                const int gk = ((kk*4 + qrot) & 15) << 3;
                short8 bh[4], bl[4];
                #pragma unroll
                for (int nt = 0; nt < 4; ++nt) {
                    const __hip_bfloat16* p = wS + (nt*16 + a15)*KP + gk;
                    bh[nt] = *(const short8*)p;
                    bl[nt] = *(const short8*)(p + ND2*KP);
                }
                #pragma unroll
                for (int nt = 0; nt < 4; ++nt) {
                    acc[nt] = __builtin_amdgcn_mfma_f32_16x16x32_bf16(afh[kk], bh[nt], acc[nt], 0, 0, 0);
                    acc[nt] = __builtin_amdgcn_mfma_f32_16x16x32_bf16(afh[kk], bl[nt], acc[nt], 0, 0, 0);
                    acc[nt] = __builtin_amdgcn_mfma_f32_16x16x32_bf16(afl[kk], bh[nt], acc[nt], 0, 0, 0);
                }
            }

            // ---- epilogue: silu, dot with fq, mask + cosine bias -> logits ----
            float lg[4];
            #pragma unroll
            for (int rg = 0; rg < 4; ++rg) {
                float l = -3.0e38f;
                float s = 0.f;
                #pragma unroll
                for (int nt = 0; nt < 4; ++nt)
                    s += fsilu(acc[nt][rg] + bfcv[nt]) * fqv[nt];
                s = red16_add(s);
                int r = tile*16 + quad*4 + rg;
                if (r < NL) {
                    float dv = s - mkv[rg];
                    float bias = c0v[rg]*rt1a + c1v[rg]*rt1b;
                    l = t20*dv + t21*bias + t22*dv*bias;
                }
                lg[rg] = l;
            }

            // ---- warp-local softmax over own 16 rows ----
            float m = fmaxf(fmaxf(lg[0], lg[1]), fmaxf(lg[2], lg[3]));
            m = swap32_max(swap16_max(m));
            float sw = 0.f;
            #pragma unroll
            for (int rg = 0; rg < 4; ++rg) {
                float p = __expf(lg[rg] - m);   // invalid rows underflow to 0
                lg[rg] = p;
                sw += p;
            }
            sw = swap32_add(swap16_add(sw));

            // ---- fv GEMM: single hi*hi pass (slot 2), reuse acc ----
            #pragma unroll
            for (int nt = 0; nt < 4; ++nt) acc[nt] = zf;
            #pragma unroll
            for (int kk = 0; kk < 4; ++kk) {
                const int gk = ((kk*4 + qrot) & 15) << 3;
                short8 bv[4];
                #pragma unroll
                for (int nt = 0; nt < 4; ++nt)
                    bv[nt] = *(const short8*)(wS + (2*ND2 + nt*16 + a15)*KP + gk);
                #pragma unroll
                for (int nt = 0; nt < 4; ++nt)
                    acc[nt] = __builtin_amdgcn_mfma_f32_16x16x32_bf16(afh[kk], bv[nt], acc[nt], 0, 0, 0);
            }

            // ---- AV: oE = sum p*silu(fv), oS = sum silu(fv) ----
            float oE[4] = {0.f,0.f,0.f,0.f}, oS[4] = {0.f,0.f,0.f,0.f};
            #pragma unroll
            for (int rg = 0; rg < 4; ++rg) {
                float p = lg[rg];
                int r = tile*16 + quad*4 + rg;
                float vm = (r < NL) ? 1.f : 0.f;
                #pragma unroll
                for (int nt = 0; nt < 4; ++nt) {
                    float sv = fsilu(acc[nt][rg] + bvcv[nt]);
                    oE[nt] += p * sv;
                    oS[nt] += vm * sv;
                }
            }
            #pragma unroll
            for (int nt = 0; nt < 4; ++nt) {
                oE[nt] = swap32_add(swap16_add(oE[nt]));
                oS[nt] = swap32_add(swap16_add(oS[nt]));
            }
            if (lane == 0) { pS[w][0] = m; pS[w][1] = sw; }
            if (quad == 0)
                #pragma unroll
                for (int nt = 0; nt < 4; ++nt) {
                    pS[w][2  + nt*16 + a15] = oE[nt];
                    pS[w][66 + nt*16 + a15] = oS[nt];
                }
        }
        __syncthreads();                        // bar1: pS ready; wS reads done

        if (h + 1 < NH) DMA(h + 1);             // restage wS (drained by bar2)

        if (w == 7) {                           // block-local LSE merge (overlaps DMA)
            const int nAct = half ? 6 : 7;
            float M = pS[0][0];
            for (int ww = 1; ww < nAct; ++ww) M = fmaxf(M, pS[ww][0]);
            float den = 0.f, num = 0.f, s1 = 0.f;
            for (int ww = 0; ww < nAct; ++ww) {
                float e = __expf(pS[ww][0] - M);
                den += e * pS[ww][1];
                num += e * pS[ww][2 + lane];
                s1  += pS[ww][66 + lane];
            }
            float* gp = gws + (((size_t)b*2 + half)*NH + h)*132;
            if (lane == 0) { gp[0] = M; gp[1] = den; }
            gp[2 + lane]  = num;
            gp[66 + lane] = s1;
        }
        __syncthreads();                        // bar2: wS(h+1) staged; pS free for reuse
    }
}

// ---------------- K4: merge the two L-halves per (b,h) ----------------
__global__ __launch_bounds__(256) void k_merge(
    const float* __restrict__ gws, float* __restrict__ out)
{
    const int b = blockIdx.x, t = threadIdx.x;
    const int h = t >> 6, d = t & 63;
    const float* A = gws + (((size_t)b*2 + 0)*NH + h)*132;
    const float* B = gws + (((size_t)b*2 + 1)*NH + h)*132;
    float MA = A[0], MB = B[0];
    float M  = fmaxf(MA, MB);
    float eA = __expf(MA - M), eB = __expf(MB - M);
    float den = eA*A[1] + eB*B[1];
    float num = eA*A[2 + d] + eB*B[2 + d];
    float s1  = A[66 + d] + B[66 + d];
    out[(size_t)b*(NH*ND2) + h*ND2 + d] = num * __fdividef(1.f, den) + 1e-7f * s1;
}

extern "C" void kernel_launch(void* const* d_in, const int* in_sizes, int n_in,
                              void* d_out, int out_size, void* d_ws, size_t ws_size,
                              hipStream_t stream) {
    const float* query = (const float*)d_in[0];
    const float* fact  = (const float*)d_in[1];
    const int*   maskp = (const int*)d_in[2];
    const float* mmc   = (const float*)d_in[3];
    const float* Wq1 = (const float*)d_in[4];
    const float* bq1 = (const float*)d_in[5];
    const float* Wq2 = (const float*)d_in[6];
    const float* bq2 = (const float*)d_in[7];
    const float* Wf1 = (const float*)d_in[8];
    const float* bf1 = (const float*)d_in[9];
    const float* Wf2 = (const float*)d_in[10];
    const float* bf2 = (const float*)d_in[11];
    const float* Wv1 = (const float*)d_in[12];
    const float* bv1 = (const float*)d_in[13];
    const float* Wv2 = (const float*)d_in[14];
    const float* bv2 = (const float*)d_in[15];
    const float* tau1 = (const float*)d_in[16];
    const float* tau2 = (const float*)d_in[17];

    char* ws = (char*)d_ws;
    float*          WQC  = (float*)(ws + OFF_WQC);
    float*          BQC  = (float*)(ws + OFF_BQC);
    float*          FQ   = (float*)(ws + OFF_FQ);
    __hip_bfloat16* WIMG = (__hip_bfloat16*)(ws + OFF_WIMG);
    float*          BFC  = (float*)(ws + OFF_BFC);
    float*          BVC  = (float*)(ws + OFF_BVC);
    float*          PART = (float*)(ws + OFF_PART);

    k_combine<<<771, 256, 0, stream>>>(Wq1, bq1, Wq2, bq2, Wf1, bf1, Wf2, bf2,
                                       Wv1, bv1, Wv2, bv2, WQC, BQC, WIMG, BFC, BVC);
    k_fq<<<NB/2, 256, 0, stream>>>(query, WQC, BQC, FQ);
    k_main<<<NB*2, NTB, 0, stream>>>(fact, maskp, mmc, tau1, tau2, FQ, BFC, BVC, WIMG,
                                     PART);
    k_merge<<<NB, 256, 0, stream>>>(PART, (float*)d_out);
}